// Round 14
// baseline (158.352 us; speedup 1.0000x reference)
//
#include <hip/hip_runtime.h>
#include <math.h>

typedef __bf16 bf16x8 __attribute__((ext_vector_type(8)));
typedef __bf16 bf16x4 __attribute__((ext_vector_type(4)));
typedef float f32x4 __attribute__((ext_vector_type(4)));

constexpr int Bb = 2, Tt = 2048, Ee = 1024, Hh = 16, Hs = 64;
constexpr int Mm = Bb * Tt;  // 4096

__device__ inline unsigned short f2bf(float f) {
    union { float f; unsigned u; } c; c.f = f;
    unsigned u = c.u;
    u += 0x7FFFu + ((u >> 16) & 1u);   // RNE
    return (unsigned short)(u >> 16);
}

#if __has_builtin(__builtin_amdgcn_exp2f)
#define EXP2(x) __builtin_amdgcn_exp2f(x)
#else
#define EXP2(x) exp2f(x)
#endif

__device__ inline void gl2lds16(const void* g, void* l) {
    __builtin_amdgcn_global_load_lds(
        (const __attribute__((address_space(1))) void*)g,
        (__attribute__((address_space(3))) void*)l, 16, 0, 0);
}

// pack two positive f32 into one dword of bf16 pair {hi=a, lo=b}, round-half-up
__device__ inline unsigned pk_bf16(float a, float b) {
    union { float f; unsigned u; } ca, cb;
    ca.f = a; cb.f = b;
    return __builtin_amdgcn_perm(ca.u + 0x8000u, cb.u + 0x8000u, 0x07060302u);
}

#define S_BARRIER() __builtin_amdgcn_s_barrier()
#define WAIT_LGKM0() asm volatile("s_waitcnt lgkmcnt(0)" ::: "memory")
#define WAIT_VM0() asm volatile("s_waitcnt vmcnt(0)" ::: "memory")

// ---------------------------------------------------------------------------
// prep: z<4 -> transpose weight z (f32 [K][N] -> bf16 [N][K]);
//       z==4 -> cast x to bf16
// ---------------------------------------------------------------------------
__global__ __launch_bounds__(256) void prep(const float* __restrict__ x,
                                            const float* __restrict__ Wq,
                                            const float* __restrict__ Wk,
                                            const float* __restrict__ Wv,
                                            const float* __restrict__ Wp,
                                            unsigned short* __restrict__ xb,
                                            unsigned short* __restrict__ wt3,
                                            unsigned short* __restrict__ wpt) {
    const int tid = threadIdx.x;
    if (blockIdx.z == 4) {
        int flat = (blockIdx.y * 16 + blockIdx.x) * 256 + tid;
#pragma unroll
        for (int i = 0; i < 16; i++) {
            int gid = flat + i * 65536;
            float4 v = ((const float4*)x)[gid];
            ushort4 o;
            o.x = f2bf(v.x); o.y = f2bf(v.y); o.z = f2bf(v.z); o.w = f2bf(v.w);
            ((ushort4*)xb)[gid] = o;
        }
        return;
    }
    __shared__ unsigned short t[64][68];
    const float* W = (blockIdx.z == 0) ? Wq : (blockIdx.z == 1) ? Wk
                    : (blockIdx.z == 2) ? Wv : Wp;
    unsigned short* dst = (blockIdx.z < 3) ? wt3 + (size_t)blockIdx.z * 1024 * 1024 : wpt;
    const int k0 = blockIdx.x * 64, n0 = blockIdx.y * 64;
#pragma unroll
    for (int j = 0; j < 4; j++) {
        int row = (tid >> 4) + j * 16;
        int c4 = (tid & 15) * 4;
        float4 v = *(const float4*)&W[(size_t)(k0 + row) * 1024 + n0 + c4];
        t[row][c4 + 0] = f2bf(v.x); t[row][c4 + 1] = f2bf(v.y);
        t[row][c4 + 2] = f2bf(v.z); t[row][c4 + 3] = f2bf(v.w);
    }
    __syncthreads();
#pragma unroll
    for (int j = 0; j < 16; j++) {
        int flat = j * 256 + tid;
        int orow = flat >> 6, ocol = flat & 63;
        dst[(size_t)(n0 + orow) * 1024 + k0 + ocol] = t[ocol][orow];
    }
}

// ---------------------------------------------------------------------------
// Fused QKV projection v3: D[4096, 3072] = xb * wt3^T.
// 256x192 tile / BK=64 / 8 waves (4Mx2N) / DOUBLE-BUFFERED issue-early
// 2-phase (guide T3 "minimum 2-phase"): per iteration
//   issue stage(t+1 -> nxt buf)          (no wait)
//   ds_read all frags from cur buf
//   lgkmcnt(0) + sched_barrier(0)        (rule #18)
//   setprio(1) 48 MFMA setprio(0)
//   vmcnt(0)                             (stage latency hidden by compute)
//   s_barrier
// 16 iterations, 16 barriers (vs R12's 32), every drain pre-covered.
// Rationale: R12 proved drain events are gemm_qkv's limiter; the m97
// single-buffer loop exposes full stage latency between two barriers.
// Geometry (stA/stB/ld*/epilogue indexing) verified on HW in R10.
// Grid 16x16 = 256 blocks = exactly 1/CU, zero tail. LDS 112KB dbuf.
// Staging traffic 384 -> 224 MB (bigger tile). kf-ascending per acc
// element -> bitwise-identical output. VGPR ~210 @ 1 block/CU, no spill.
// Q epilogue folds (1/32)*log2(e).
// ---------------------------------------------------------------------------
__global__ __launch_bounds__(512, 1) void gemm_qkv(const unsigned short* __restrict__ A,
                                                   const unsigned short* __restrict__ Bt,
                                                   unsigned short* __restrict__ qb,
                                                   unsigned short* __restrict__ kb,
                                                   unsigned short* __restrict__ vtb) {
    __shared__ unsigned short As[2][16384];  // 2 x 256rows x 64 (32KB each)
    __shared__ unsigned short Bs[2][12288];  // 2 x 192rows x 64 (24KB each)
    const int tid = threadIdx.x;
    const int bm = blockIdx.y * 256;
    const int bn = blockIdx.x * 192;
    const int lane = tid & 63, w = tid >> 6;
    const int quad = lane >> 4, cl = lane & 15;
    const int wm = (w >> 1) * 64;   // 4 m-slots of 64 rows
    const int wn = (w & 1) * 96;    // 2 n-slots of 96 cols

    f32x4 acc[4][6] = {};
    bf16x8 a[4][2];   // 4 m-frags x 2 kf
    bf16x8 b[6][2];   // 6 n-frags x 2 kf

    const int sr = tid >> 3, ss = tid & 7;
    const int sc = ss ^ (sr & 7);   // pre-swizzled source chunk, linear dest

    auto stA = [&](int buf, int u, int kt) {
        gl2lds16(A + (size_t)(bm + u * 64 + sr) * 1024 + kt * 64 + sc * 8,
                 &As[buf][u * 4096 + tid * 8]);
    };
    auto stB = [&](int buf, int u, int kt) {
        gl2lds16(Bt + (size_t)(bn + u * 64 + sr) * 1024 + kt * 64 + sc * 8,
                 &Bs[buf][u * 4096 + tid * 8]);
    };
    auto stageAll = [&](int buf, int kt) {
        stB(buf, 0, kt); stB(buf, 1, kt); stB(buf, 2, kt);
        stA(buf, 0, kt); stA(buf, 1, kt); stA(buf, 2, kt); stA(buf, 3, kt);
    };

    // prologue: buf0 <- kt0, wait, barrier
    stageAll(0, 0);
    WAIT_VM0();
    S_BARRIER();

    for (int t = 0; t < 16; ++t) {
        const int cur = t & 1, nxt = cur ^ 1;
        const bool pf = (t < 15);
        if (pf) stageAll(nxt, t + 1);     // issue early; no wait

        // ds_read all fragments from cur
#pragma unroll
        for (int mt = 0; mt < 4; mt++) {
            int R = wm + mt * 16 + cl;
#pragma unroll
            for (int kf = 0; kf < 2; kf++) {
                int cc = kf * 4 + quad;
                a[mt][kf] = *(const bf16x8*)&As[cur][(R * 8 + (cc ^ (R & 7))) * 8];
            }
        }
#pragma unroll
        for (int nt = 0; nt < 6; nt++) {
            int R = wn + nt * 16 + cl;
#pragma unroll
            for (int kf = 0; kf < 2; kf++) {
                int cc = kf * 4 + quad;
                b[nt][kf] = *(const bf16x8*)&Bs[cur][(R * 8 + (cc ^ (R & 7))) * 8];
            }
        }
        WAIT_LGKM0();
        __builtin_amdgcn_sched_barrier(0);    // rule #18: pin MFMA after wait
        __builtin_amdgcn_s_setprio(1);
#pragma unroll
        for (int kf = 0; kf < 2; kf++)
#pragma unroll
            for (int mt = 0; mt < 4; mt++)
#pragma unroll
                for (int nt = 0; nt < 6; nt++)
                    acc[mt][nt] = __builtin_amdgcn_mfma_f32_16x16x32_bf16(
                        a[mt][kf], b[nt][kf], acc[mt][nt], 0, 0, 0);
        __builtin_amdgcn_s_setprio(0);

        if (pf) WAIT_VM0();                   // next buf resident (latency hidden)
        S_BARRIER();
    }

    // epilogue: region per n-frag (cols may span Q/K/V 1024-boundaries)
#pragma unroll
    for (int ni = 0; ni < 6; ni++) {
        int ncol = bn + wn + ni * 16 + cl;     // 0..3071
        int region = (bn + wn + ni * 16) >> 10; // wave-uniform (16-aligned)
        int nn = ncol & 1023;
        int h = nn >> 6, hs = nn & 63;
        if (region < 2) {
            unsigned short* dst = region ? kb : qb;
            const float qs = region ? 1.0f : 0.045084220027780107f;  // (1/32)*log2e
#pragma unroll
            for (int mi = 0; mi < 4; mi++)
#pragma unroll
                for (int rg = 0; rg < 4; rg++) {
                    int m = bm + wm + mi * 16 + quad * 4 + rg;
                    int b2 = m >> 11, t = m & 2047;
                    dst[((size_t)(b2 * 16 + h) * 2048 + t) * 64 + hs] =
                        f2bf(acc[mi][ni][rg] * qs);
                }
        } else {
#pragma unroll
            for (int mi = 0; mi < 4; mi++) {
                int m0 = bm + wm + mi * 16 + quad * 4;
                int b2 = m0 >> 11, t0 = m0 & 2047;
                ushort4 pk;
                pk.x = f2bf(acc[mi][ni][0]); pk.y = f2bf(acc[mi][ni][1]);
                pk.z = f2bf(acc[mi][ni][2]); pk.w = f2bf(acc[mi][ni][3]);
                *(ushort4*)&vtb[((size_t)(b2 * 16 + h) * 64 + hs) * 2048 + t0] = pk;
            }
        }
    }
}

// ---------------------------------------------------------------------------
// Final projection: out[4096,1024] fp32 = ab * wpt^T + bias. 64x128 tiles
// / BK=64 (R13). LDS 24KB. T1 XCD-chunked swizzle (512 blocks, bijective).
// ---------------------------------------------------------------------------
__global__ __launch_bounds__(256, 4) void gemm_out(const unsigned short* __restrict__ A,
                                                   const unsigned short* __restrict__ Bt,
                                                   const float* __restrict__ bias,
                                                   float* __restrict__ out) {
    __shared__ unsigned short As[64 * 64];   // 8 KB
    __shared__ unsigned short Bs[128 * 64];  // 16 KB
    const int tid = threadIdx.x;
    const int bid = blockIdx.x;
    const int swz = (bid & 7) * 64 + (bid >> 3);  // XCD-chunked, bijective
    const int bx = swz & 7, by = swz >> 3;
    const int bm = by * 64;
    const int bn = bx * 128;
    const int lane = tid & 63, w = tid >> 6;
    const int quad = lane >> 4, cl = lane & 15;
    const int wm = (w >> 1) * 32, wn = (w & 1) * 64;
    f32x4 acc[2][4] = {};

    auto stage = [&](int k0) {
#pragma unroll
        for (int i = 0; i < 2; i++) {         // As: 64 rows x 8 chunks = 512
            int L = tid + i * 256;
            int r = L >> 3, s = L & 7;
            int c = s ^ (r & 7);
            gl2lds16(A + (size_t)(bm + r) * 1024 + k0 + c * 8, &As[L * 8]);
        }
#pragma unroll
        for (int i = 0; i < 4; i++) {         // Bs: 128 rows x 8 chunks = 1024
            int L = tid + i * 256;
            int r = L >> 3, s = L & 7;
            int c = s ^ (r & 7);
            gl2lds16(Bt + (size_t)(bn + r) * 1024 + k0 + c * 8, &Bs[L * 8]);
        }
    };

    stage(0);
    __syncthreads();
    for (int k0 = 0;;) {
#pragma unroll
        for (int kf = 0; kf < 2; kf++) {      // two BK=32 sub-phases
            bf16x8 af[2], bfr[4];
            const int cc = kf * 4 + quad;
#pragma unroll
            for (int mt = 0; mt < 2; mt++) {
                int r = wm + mt * 16 + cl;
                af[mt] = *(const bf16x8*)&As[(r * 8 + (cc ^ (r & 7))) * 8];
            }
#pragma unroll
            for (int nt = 0; nt < 4; nt++) {
                int rb = wn + nt * 16 + cl;
                bfr[nt] = *(const bf16x8*)&Bs[(rb * 8 + (cc ^ (rb & 7))) * 8];
            }
#pragma unroll
            for (int mt = 0; mt < 2; mt++)
#pragma unroll
                for (int nt = 0; nt < 4; nt++)
                    acc[mt][nt] = __builtin_amdgcn_mfma_f32_16x16x32_bf16(
                        af[mt], bfr[nt], acc[mt][nt], 0, 0, 0);
        }
        k0 += 64;
        if (k0 >= 1024) break;
        __syncthreads();
        stage(k0);
        __syncthreads();
    }

#pragma unroll
    for (int mt = 0; mt < 2; mt++)
#pragma unroll
        for (int nt = 0; nt < 4; nt++)
#pragma unroll
            for (int rg = 0; rg < 4; rg++) {
                int m = bm + wm + mt * 16 + quad * 4 + rg;
                int n = bn + wn + nt * 16 + cl;
                out[(size_t)m * 1024 + n] = acc[mt][nt][rg] + bias[n];
            }
}

// ---------------------------------------------------------------------------
// MFMA flash attention v8: two q-tiles per block with SHARED K/V staging.
// Block (bh, j): waves 0-3 handle qt=j, waves 4-7 handle qt=31-j, both
// reading the same 4-buffer rotating K/V staged to the long tile's range.
// In-register P via K-row staging permutation (LDS row r holds key grow(r):
// r5r4r3r2r1r0 -> r5r3r2r4r1r0) -> no P buffer, no bank conflicts.
// LDS 64KB -> 2 blocks/CU = 16 waves/CU. setprio on MFMA clusters.
// Grid 512 longest-first; same-bh blocks already share an XCD (idx%8==bh%8).
// ---------------------------------------------------------------------------
__global__ __launch_bounds__(512, 2) void attn_mfma(const unsigned short* __restrict__ qg,
                                                    const unsigned short* __restrict__ kg,
                                                    const unsigned short* __restrict__ vtg,
                                                    unsigned short* __restrict__ og) {
    __shared__ unsigned short lds[32768];  // 64 KB: K bufs 4x4096 | V bufs 4x4096

    const int tid = threadIdx.x;
    const int idx = blockIdx.x;
    const int bh = idx & 31;
    const int j = idx >> 5;                // 0..15, longest-duration-first
    const int lane = tid & 63, w = tid >> 6;
    const int quad = lane >> 4, cl = lane & 15;
    const int g = w >> 2;                  // q-group: 0 -> qt=j, 1 -> qt=31-j
    const int qt = g ? (31 - j) : j;
    const int p = (w >> 1) & 1;            // k-tile parity within group
    const int qhalf = w & 1;               // which 32 q-rows of the group's 64
    const int qbase = qt * 64;
    const int qtL = 31 - j;                // long tile bound governs staging
    const unsigned short* qB = qg + (size_t)bh * 2048 * 64;
    const unsigned short* kB = kg + (size_t)bh * 2048 * 64;
    const unsigned short* vB = vtg + (size_t)bh * 64 * 2048;

    // combine scratch (valid only after main loop): per group 18KB region
    float* Cmb = (float*)lds + g * 4608;   // [64][stride 68] f32
    float* Ll = Cmb + 4352;                // 64 f32

    auto stageKV = [&](int kt) {
        unsigned short* Kd = lds + (kt & 3) * 4096;
        unsigned short* Vd = lds + 16384 + (kt & 3) * 4096;
        int L = tid;                       // 512 threads: 1 load each for K, V
        int r = L >> 3;
        int kc = (L & 7) ^ (r & 7);
        // K row permutation: LDS row r holds global key row grow(r) so the
        // QK C-layout lands directly in PV A-fragment key order.
        int grow = (r & 32) | ((r & 12) << 1) | ((r & 16) >> 2) | (r & 3);
        gl2lds16(kB + (size_t)(kt * 64 + grow) * 64 + kc * 8, &Kd[L * 8]);
        gl2lds16(vB + (size_t)r * 2048 + kt * 64 + kc * 8, &Vd[L * 8]);
    };

    // Q fragments straight from global (B-operand layout; 16B loads)
    bf16x8 qf[2][2];
#pragma unroll
    for (int nt2 = 0; nt2 < 2; nt2++)
#pragma unroll
        for (int kf = 0; kf < 2; kf++) {
            int row = qbase + qhalf * 32 + nt2 * 16 + cl;
            qf[nt2][kf] = *(const bf16x8*)&qB[(size_t)row * 64 + (kf * 4 + quad) * 8];
        }

    bf16x8 ones;
#pragma unroll
    for (int i = 0; i < 8; i++) ones[i] = (__bf16)1.0f;

    f32x4 oacc[2][4] = {};
    f32x4 lacc[2] = {};
    const int nit = (qtL + 2) >> 1;

    stageKV(0);
    stageKV(1);                            // qtL >= 16, always valid
    __syncthreads();

    for (int i = 0; i < nit; i++) {
        // prefetch next iteration's tiles into the rotating buffers
        if (2 * i + 2 <= qtL) stageKV(2 * i + 2);
        if (2 * i + 3 <= qtL) stageKV(2 * i + 3);

        const int kt = 2 * i + p;
        if (kt <= qt) {                    // wave-level skip (group-local qt)
            const bool diag = (kt == qt);
            const unsigned short* Kl = lds + (kt & 3) * 4096;
            const unsigned short* Vl = lds + 16384 + (kt & 3) * 4096;
            // ---- S^T = K Q^T : C row r = score of key grow(r) ----
            f32x4 sac[4][2] = {};
            __builtin_amdgcn_s_setprio(1);
#pragma unroll
            for (int kf = 0; kf < 2; kf++)
#pragma unroll
                for (int mt = 0; mt < 4; mt++) {
                    int r = mt * 16 + cl, cc = kf * 4 + quad;
                    bf16x8 kf8 = *(const bf16x8*)&Kl[(r * 8 + (cc ^ (r & 7))) * 8];
#pragma unroll
                    for (int nt2 = 0; nt2 < 2; nt2++)
                        sac[mt][nt2] = __builtin_amdgcn_mfma_f32_16x16x32_bf16(
                            kf8, qf[nt2][kf], sac[mt][nt2], 0, 0, 0);
                }
            __builtin_amdgcn_s_setprio(0);
            // ---- two passes of 32 keys: exp2 + pack; pf entirely in-reg ----
#pragma unroll
            for (int ks = 0; ks < 2; ks++) {
                bf16x8 pf[2];
#pragma unroll
                for (int nt2 = 0; nt2 < 2; nt2++) {
                    unsigned dw[4];
#pragma unroll
                    for (int mtl = 0; mtl < 2; mtl++) {
                        float pv[4];
#pragma unroll
                        for (int rg = 0; rg < 4; rg++) {
                            float e = EXP2(sac[ks * 2 + mtl][nt2][rg]);
                            // permuted C-row: key = ks*32 + quad*8 + mtl*4 + rg
                            if (diag && (ks * 32 + quad * 8 + mtl * 4 + rg >
                                         nt2 * 16 + cl + qhalf * 32))
                                e = 0.0f;
                            pv[rg] = e;
                        }
                        dw[mtl * 2 + 0] = pk_bf16(pv[1], pv[0]);  // keys +0,+1
                        dw[mtl * 2 + 1] = pk_bf16(pv[3], pv[2]);  // keys +2,+3
                    }
                    union { uint4 u; bf16x8 v; } cv;
                    cv.u = make_uint4(dw[0], dw[1], dw[2], dw[3]);
                    pf[nt2] = cv.v;
                }
                // PV: O += P V ; l += P.1   (k = 32 keys of this pass)
                __builtin_amdgcn_s_setprio(1);
#pragma unroll
                for (int mt2 = 0; mt2 < 2; mt2++)
                    lacc[mt2] = __builtin_amdgcn_mfma_f32_16x16x32_bf16(
                        pf[mt2], ones, lacc[mt2], 0, 0, 0);
#pragma unroll
                for (int nt = 0; nt < 4; nt++) {
                    int r = nt * 16 + cl, cc = ks * 4 + quad;
                    bf16x8 vf = *(const bf16x8*)&Vl[(r * 8 + (cc ^ (r & 7))) * 8];
#pragma unroll
                    for (int mt2 = 0; mt2 < 2; mt2++)
                        oacc[mt2][nt] = __builtin_amdgcn_mfma_f32_16x16x32_bf16(
                            pf[mt2], vf, oacc[mt2][nt], 0, 0, 0);
                }
                __builtin_amdgcn_s_setprio(0);
            }
        }
        __syncthreads();  // drains this iteration's prefetch; syncs buffers
    }

    // ---- pair combine per group: p=1 writes partials, p=0 adds + stores ----
    if (p == 1) {
#pragma unroll
        for (int mt2 = 0; mt2 < 2; mt2++)
#pragma unroll
            for (int rg = 0; rg < 4; rg++) {
                int row = qhalf * 32 + mt2 * 16 + quad * 4 + rg;
                if (cl == 0) Ll[row] = lacc[mt2][rg];
#pragma unroll
                for (int nt = 0; nt < 4; nt++)
                    Cmb[row * 68 + nt * 16 + cl] = oacc[mt2][nt][rg];
            }
    }
    __syncthreads();
    if (p == 0) {
        const int b = bh >> 4, h = bh & 15;
#pragma unroll
        for (int mt2 = 0; mt2 < 2; mt2++)
#pragma unroll
            for (int rg = 0; rg < 4; rg++) {
                int row = qhalf * 32 + mt2 * 16 + quad * 4 + rg;
                float inv = 1.0f / (lacc[mt2][rg] + Ll[row]);
                int t = qbase + row;
#pragma unroll
                for (int nt = 0; nt < 4; nt++) {
                    int hs = nt * 16 + cl;
                    float val = oacc[mt2][nt][rg] + Cmb[row * 68 + nt * 16 + cl];
                    og[((size_t)(b * 2048 + t)) * 1024 + h * 64 + hs] = f2bf(val * inv);
                }
            }
    }
}

// ---------------------------------------------------------------------------
extern "C" void kernel_launch(void* const* d_in, const int* in_sizes, int n_in,
                              void* d_out, int out_size, void* d_ws, size_t ws_size,
                              hipStream_t stream) {
    const float* x = (const float*)d_in[0];
    const float* Wq = (const float*)d_in[1];
    const float* Wk = (const float*)d_in[2];
    const float* Wv = (const float*)d_in[3];
    const float* Wp = (const float*)d_in[4];
    const float* bp = (const float*)d_in[5];
    float* out = (float*)d_out;

    unsigned short* xb = (unsigned short*)d_ws;      // 8 MB
    unsigned short* wt3 = xb + (size_t)Mm * Ee;      // 6 MB (Q,K,V transposed)
    unsigned short* wpt = wt3 + (size_t)3 * Ee * Ee; // 2 MB
    unsigned short* qb = wpt + (size_t)Ee * Ee;      // 8 MB each
    unsigned short* kb = qb + (size_t)Mm * Ee;
    unsigned short* vtb = kb + (size_t)Mm * Ee;
    unsigned short* ab = vtb + (size_t)Mm * Ee;

    prep<<<dim3(16, 16, 5), dim3(256), 0, stream>>>(x, Wq, Wk, Wv, Wp, xb, wt3, wpt);
    gemm_qkv<<<dim3(16, 16), dim3(512), 0, stream>>>(xb, wt3, qb, kb, vtb);
    attn_mfma<<<dim3(512), dim3(512), 0, stream>>>(qb, kb, vtb, ab);
    gemm_out<<<dim3(512), dim3(256), 0, stream>>>(ab, wpt, bp, out);
}

// Round 15
// 156.068 us; speedup vs baseline: 1.0146x; 1.0146x over previous
//
#include <hip/hip_runtime.h>
#include <math.h>

typedef __bf16 bf16x8 __attribute__((ext_vector_type(8)));
typedef __bf16 bf16x4 __attribute__((ext_vector_type(4)));
typedef float f32x4 __attribute__((ext_vector_type(4)));

constexpr int Bb = 2, Tt = 2048, Ee = 1024, Hh = 16, Hs = 64;
constexpr int Mm = Bb * Tt;  // 4096

__device__ inline unsigned short f2bf(float f) {
    union { float f; unsigned u; } c; c.f = f;
    unsigned u = c.u;
    u += 0x7FFFu + ((u >> 16) & 1u);   // RNE
    return (unsigned short)(u >> 16);
}

#if __has_builtin(__builtin_amdgcn_exp2f)
#define EXP2(x) __builtin_amdgcn_exp2f(x)
#else
#define EXP2(x) exp2f(x)
#endif

__device__ inline void gl2lds16(const void* g, void* l) {
    __builtin_amdgcn_global_load_lds(
        (const __attribute__((address_space(1))) void*)g,
        (__attribute__((address_space(3))) void*)l, 16, 0, 0);
}

// pack two positive f32 into one dword of bf16 pair {hi=a, lo=b}, round-half-up
__device__ inline unsigned pk_bf16(float a, float b) {
    union { float f; unsigned u; } ca, cb;
    ca.f = a; cb.f = b;
    return __builtin_amdgcn_perm(ca.u + 0x8000u, cb.u + 0x8000u, 0x07060302u);
}

// ---------------------------------------------------------------------------
// prep: z<4 -> transpose weight z (f32 [K][N] -> bf16 [N][K]);
//       z==4 -> cast x to bf16
// ---------------------------------------------------------------------------
__global__ __launch_bounds__(256) void prep(const float* __restrict__ x,
                                            const float* __restrict__ Wq,
                                            const float* __restrict__ Wk,
                                            const float* __restrict__ Wv,
                                            const float* __restrict__ Wp,
                                            unsigned short* __restrict__ xb,
                                            unsigned short* __restrict__ wt3,
                                            unsigned short* __restrict__ wpt) {
    const int tid = threadIdx.x;
    if (blockIdx.z == 4) {
        int flat = (blockIdx.y * 16 + blockIdx.x) * 256 + tid;
#pragma unroll
        for (int i = 0; i < 16; i++) {
            int gid = flat + i * 65536;
            float4 v = ((const float4*)x)[gid];
            ushort4 o;
            o.x = f2bf(v.x); o.y = f2bf(v.y); o.z = f2bf(v.z); o.w = f2bf(v.w);
            ((ushort4*)xb)[gid] = o;
        }
        return;
    }
    __shared__ unsigned short t[64][68];
    const float* W = (blockIdx.z == 0) ? Wq : (blockIdx.z == 1) ? Wk
                    : (blockIdx.z == 2) ? Wv : Wp;
    unsigned short* dst = (blockIdx.z < 3) ? wt3 + (size_t)blockIdx.z * 1024 * 1024 : wpt;
    const int k0 = blockIdx.x * 64, n0 = blockIdx.y * 64;
#pragma unroll
    for (int j = 0; j < 4; j++) {
        int row = (tid >> 4) + j * 16;
        int c4 = (tid & 15) * 4;
        float4 v = *(const float4*)&W[(size_t)(k0 + row) * 1024 + n0 + c4];
        t[row][c4 + 0] = f2bf(v.x); t[row][c4 + 1] = f2bf(v.y);
        t[row][c4 + 2] = f2bf(v.z); t[row][c4 + 3] = f2bf(v.w);
    }
    __syncthreads();
#pragma unroll
    for (int j = 0; j < 16; j++) {
        int flat = j * 256 + tid;
        int orow = flat >> 6, ocol = flat & 63;
        dst[(size_t)(n0 + orow) * 1024 + k0 + ocol] = t[ocol][orow];
    }
}

// ---------------------------------------------------------------------------
// Fused QKV projection: D[4096, 3072] = xb * wt3^T.
// 128x128 tile / BK=64 / 2-barrier m97 pattern (R12 WIN: halving the
// vmcnt-drain count 32->16 per block was the lever; -5.7us total).
// Inner K=64 as two BK=32 sub-phases sharing fragment regs. 8-chunk rows,
// swizzle c = s ^ (r&7) on stage-source and read (2 lanes/bank = free).
// T1 XCD-chunked block swizzle retained. Q epilogue folds (1/32)*log2(e).
// Session note (R14): five gemm_qkv structures all plateau ~36us; this is
// the best verified. Path beyond is inline-asm K-loop scheduling.
// ---------------------------------------------------------------------------
__global__ __launch_bounds__(256, 3) void gemm_qkv(const unsigned short* __restrict__ A,
                                                   const unsigned short* __restrict__ Bt,
                                                   unsigned short* __restrict__ qb,
                                                   unsigned short* __restrict__ kb,
                                                   unsigned short* __restrict__ vtb) {
    __shared__ unsigned short As[128 * 64];  // 16 KB
    __shared__ unsigned short Bs[128 * 64];  // 16 KB
    const int tid = threadIdx.x;
    const int bid = blockIdx.x;
    const int swz = (bid & 7) * 96 + (bid >> 3);  // XCD-chunked, bijective
    const int bx = swz % 24, by = swz / 24;
    const int bm = by * 128;
    const int bn = bx * 128;
    const int lane = tid & 63, w = tid >> 6;
    const int quad = lane >> 4, cl = lane & 15;
    const int wm = (w >> 1) * 64, wn = (w & 1) * 64;
    f32x4 acc[4][4] = {};

    auto stage = [&](int k0) {
#pragma unroll
        for (int i = 0; i < 4; i++) {
            int L = tid + i * 256;            // 0..1023 = 128 rows x 8 chunks
            int r = L >> 3, s = L & 7;
            int c = s ^ (r & 7);              // pre-swizzled source chunk
            gl2lds16(A + (size_t)(bm + r) * 1024 + k0 + c * 8, &As[L * 8]);
        }
#pragma unroll
        for (int i = 0; i < 4; i++) {
            int L = tid + i * 256;
            int r = L >> 3, s = L & 7;
            int c = s ^ (r & 7);
            gl2lds16(Bt + (size_t)(bn + r) * 1024 + k0 + c * 8, &Bs[L * 8]);
        }
    };

    stage(0);
    __syncthreads();
    for (int k0 = 0;;) {
#pragma unroll
        for (int kf = 0; kf < 2; kf++) {      // two BK=32 sub-phases
            bf16x8 af[4], bfr[4];
            const int cc = kf * 4 + quad;
#pragma unroll
            for (int mt = 0; mt < 4; mt++) {
                int r = wm + mt * 16 + cl;
                af[mt] = *(const bf16x8*)&As[(r * 8 + (cc ^ (r & 7))) * 8];
                int rb = wn + mt * 16 + cl;
                bfr[mt] = *(const bf16x8*)&Bs[(rb * 8 + (cc ^ (rb & 7))) * 8];
            }
#pragma unroll
            for (int mt = 0; mt < 4; mt++)
#pragma unroll
                for (int nt = 0; nt < 4; nt++)
                    acc[mt][nt] = __builtin_amdgcn_mfma_f32_16x16x32_bf16(
                        af[mt], bfr[nt], acc[mt][nt], 0, 0, 0);
        }
        k0 += 64;
        if (k0 >= 1024) break;
        __syncthreads();
        stage(k0);
        __syncthreads();
    }

    const int region = bn >> 10;
    if (region < 2) {
        unsigned short* dst = region ? kb : qb;
        const float qs = region ? 1.0f : 0.045084220027780107f;  // (1/32)*log2e
#pragma unroll
        for (int mt = 0; mt < 4; mt++)
#pragma unroll
            for (int nt = 0; nt < 4; nt++)
#pragma unroll
                for (int rg = 0; rg < 4; rg++) {
                    int m = bm + wm + mt * 16 + quad * 4 + rg;
                    int nn = (bn + wn + nt * 16 + cl) & 1023;
                    int b = m >> 11, t = m & 2047, h = nn >> 6, hs = nn & 63;
                    dst[((size_t)(b * 16 + h) * 2048 + t) * 64 + hs] =
                        f2bf(acc[mt][nt][rg] * qs);
                }
    } else {
#pragma unroll
        for (int mt = 0; mt < 4; mt++) {
            int m0 = bm + wm + mt * 16 + quad * 4;
            int b = m0 >> 11, t0 = m0 & 2047;
#pragma unroll
            for (int nt = 0; nt < 4; nt++) {
                int nn = (bn + wn + nt * 16 + cl) & 1023;
                int h = nn >> 6, hs = nn & 63;
                ushort4 pk;
                pk.x = f2bf(acc[mt][nt][0]); pk.y = f2bf(acc[mt][nt][1]);
                pk.z = f2bf(acc[mt][nt][2]); pk.w = f2bf(acc[mt][nt][3]);
                *(ushort4*)&vtb[((size_t)(b * 16 + h) * 64 + hs) * 2048 + t0] = pk;
            }
        }
    }
}

// ---------------------------------------------------------------------------
// Final projection: out[4096,1024] fp32 = ab * wpt^T + bias. 64x128 tiles
// / BK=64 (R13: drain-halving 32 -> 16 per block). LDS 24KB.
// T1 XCD-chunked swizzle (512 blocks, 64/XCD, bijective).
// ---------------------------------------------------------------------------
__global__ __launch_bounds__(256, 4) void gemm_out(const unsigned short* __restrict__ A,
                                                   const unsigned short* __restrict__ Bt,
                                                   const float* __restrict__ bias,
                                                   float* __restrict__ out) {
    __shared__ unsigned short As[64 * 64];   // 8 KB
    __shared__ unsigned short Bs[128 * 64];  // 16 KB
    const int tid = threadIdx.x;
    const int bid = blockIdx.x;
    const int swz = (bid & 7) * 64 + (bid >> 3);  // XCD-chunked, bijective
    const int bx = swz & 7, by = swz >> 3;
    const int bm = by * 64;
    const int bn = bx * 128;
    const int lane = tid & 63, w = tid >> 6;
    const int quad = lane >> 4, cl = lane & 15;
    const int wm = (w >> 1) * 32, wn = (w & 1) * 64;
    f32x4 acc[2][4] = {};

    auto stage = [&](int k0) {
#pragma unroll
        for (int i = 0; i < 2; i++) {         // As: 64 rows x 8 chunks = 512
            int L = tid + i * 256;
            int r = L >> 3, s = L & 7;
            int c = s ^ (r & 7);
            gl2lds16(A + (size_t)(bm + r) * 1024 + k0 + c * 8, &As[L * 8]);
        }
#pragma unroll
        for (int i = 0; i < 4; i++) {         // Bs: 128 rows x 8 chunks = 1024
            int L = tid + i * 256;
            int r = L >> 3, s = L & 7;
            int c = s ^ (r & 7);
            gl2lds16(Bt + (size_t)(bn + r) * 1024 + k0 + c * 8, &Bs[L * 8]);
        }
    };

    stage(0);
    __syncthreads();
    for (int k0 = 0;;) {
#pragma unroll
        for (int kf = 0; kf < 2; kf++) {      // two BK=32 sub-phases
            bf16x8 af[2], bfr[4];
            const int cc = kf * 4 + quad;
#pragma unroll
            for (int mt = 0; mt < 2; mt++) {
                int r = wm + mt * 16 + cl;
                af[mt] = *(const bf16x8*)&As[(r * 8 + (cc ^ (r & 7))) * 8];
            }
#pragma unroll
            for (int nt = 0; nt < 4; nt++) {
                int rb = wn + nt * 16 + cl;
                bfr[nt] = *(const bf16x8*)&Bs[(rb * 8 + (cc ^ (rb & 7))) * 8];
            }
#pragma unroll
            for (int mt = 0; mt < 2; mt++)
#pragma unroll
                for (int nt = 0; nt < 4; nt++)
                    acc[mt][nt] = __builtin_amdgcn_mfma_f32_16x16x32_bf16(
                        af[mt], bfr[nt], acc[mt][nt], 0, 0, 0);
        }
        k0 += 64;
        if (k0 >= 1024) break;
        __syncthreads();
        stage(k0);
        __syncthreads();
    }

#pragma unroll
    for (int mt = 0; mt < 2; mt++)
#pragma unroll
        for (int nt = 0; nt < 4; nt++)
#pragma unroll
            for (int rg = 0; rg < 4; rg++) {
                int m = bm + wm + mt * 16 + quad * 4 + rg;
                int n = bn + wn + nt * 16 + cl;
                out[(size_t)m * 1024 + n] = acc[mt][nt][rg] + bias[n];
            }
}

// ---------------------------------------------------------------------------
// MFMA flash attention v8: two q-tiles per block with SHARED K/V staging.
// Block (bh, j): waves 0-3 handle qt=j, waves 4-7 handle qt=31-j, both
// reading the same 4-buffer rotating K/V staged to the long tile's range.
// In-register P via K-row staging permutation (LDS row r holds key grow(r):
// r5r4r3r2r1r0 -> r5r3r2r4r1r0) -> no P buffer, no bank conflicts.
// LDS 64KB -> 2 blocks/CU = 16 waves/CU. setprio on MFMA clusters.
// Grid 512 longest-first; same-bh blocks already share an XCD (idx%8==bh%8).
// (v9 lesson: 3 blocks/CU needs VGPR<=85 < ~110 live regs -> spills; the
// occupancy ladder for this shape ends at 16 waves/CU.)
// ---------------------------------------------------------------------------
__global__ __launch_bounds__(512, 2) void attn_mfma(const unsigned short* __restrict__ qg,
                                                    const unsigned short* __restrict__ kg,
                                                    const unsigned short* __restrict__ vtg,
                                                    unsigned short* __restrict__ og) {
    __shared__ unsigned short lds[32768];  // 64 KB: K bufs 4x4096 | V bufs 4x4096

    const int tid = threadIdx.x;
    const int idx = blockIdx.x;
    const int bh = idx & 31;
    const int j = idx >> 5;                // 0..15, longest-duration-first
    const int lane = tid & 63, w = tid >> 6;
    const int quad = lane >> 4, cl = lane & 15;
    const int g = w >> 2;                  // q-group: 0 -> qt=j, 1 -> qt=31-j
    const int qt = g ? (31 - j) : j;
    const int p = (w >> 1) & 1;            // k-tile parity within group
    const int qhalf = w & 1;               // which 32 q-rows of the group's 64
    const int qbase = qt * 64;
    const int qtL = 31 - j;                // long tile bound governs staging
    const unsigned short* qB = qg + (size_t)bh * 2048 * 64;
    const unsigned short* kB = kg + (size_t)bh * 2048 * 64;
    const unsigned short* vB = vtg + (size_t)bh * 64 * 2048;

    // combine scratch (valid only after main loop): per group 18KB region
    float* Cmb = (float*)lds + g * 4608;   // [64][stride 68] f32
    float* Ll = Cmb + 4352;                // 64 f32

    auto stageKV = [&](int kt) {
        unsigned short* Kd = lds + (kt & 3) * 4096;
        unsigned short* Vd = lds + 16384 + (kt & 3) * 4096;
        int L = tid;                       // 512 threads: 1 load each for K, V
        int r = L >> 3;
        int kc = (L & 7) ^ (r & 7);
        // K row permutation: LDS row r holds global key row grow(r) so the
        // QK C-layout lands directly in PV A-fragment key order.
        int grow = (r & 32) | ((r & 12) << 1) | ((r & 16) >> 2) | (r & 3);
        gl2lds16(kB + (size_t)(kt * 64 + grow) * 64 + kc * 8, &Kd[L * 8]);
        gl2lds16(vB + (size_t)r * 2048 + kt * 64 + kc * 8, &Vd[L * 8]);
    };

    // Q fragments straight from global (B-operand layout; 16B loads)
    bf16x8 qf[2][2];
#pragma unroll
    for (int nt2 = 0; nt2 < 2; nt2++)
#pragma unroll
        for (int kf = 0; kf < 2; kf++) {
            int row = qbase + qhalf * 32 + nt2 * 16 + cl;
            qf[nt2][kf] = *(const bf16x8*)&qB[(size_t)row * 64 + (kf * 4 + quad) * 8];
        }

    bf16x8 ones;
#pragma unroll
    for (int i = 0; i < 8; i++) ones[i] = (__bf16)1.0f;

    f32x4 oacc[2][4] = {};
    f32x4 lacc[2] = {};
    const int nit = (qtL + 2) >> 1;

    stageKV(0);
    stageKV(1);                            // qtL >= 16, always valid
    __syncthreads();

    for (int i = 0; i < nit; i++) {
        // prefetch next iteration's tiles into the rotating buffers
        if (2 * i + 2 <= qtL) stageKV(2 * i + 2);
        if (2 * i + 3 <= qtL) stageKV(2 * i + 3);

        const int kt = 2 * i + p;
        if (kt <= qt) {                    // wave-level skip (group-local qt)
            const bool diag = (kt == qt);
            const unsigned short* Kl = lds + (kt & 3) * 4096;
            const unsigned short* Vl = lds + 16384 + (kt & 3) * 4096;
            // ---- S^T = K Q^T : C row r = score of key grow(r) ----
            f32x4 sac[4][2] = {};
            __builtin_amdgcn_s_setprio(1);
#pragma unroll
            for (int kf = 0; kf < 2; kf++)
#pragma unroll
                for (int mt = 0; mt < 4; mt++) {
                    int r = mt * 16 + cl, cc = kf * 4 + quad;
                    bf16x8 kf8 = *(const bf16x8*)&Kl[(r * 8 + (cc ^ (r & 7))) * 8];
#pragma unroll
                    for (int nt2 = 0; nt2 < 2; nt2++)
                        sac[mt][nt2] = __builtin_amdgcn_mfma_f32_16x16x32_bf16(
                            kf8, qf[nt2][kf], sac[mt][nt2], 0, 0, 0);
                }
            __builtin_amdgcn_s_setprio(0);
            // ---- two passes of 32 keys: exp2 + pack; pf entirely in-reg ----
#pragma unroll
            for (int ks = 0; ks < 2; ks++) {
                bf16x8 pf[2];
#pragma unroll
                for (int nt2 = 0; nt2 < 2; nt2++) {
                    unsigned dw[4];
#pragma unroll
                    for (int mtl = 0; mtl < 2; mtl++) {
                        float pv[4];
#pragma unroll
                        for (int rg = 0; rg < 4; rg++) {
                            float e = EXP2(sac[ks * 2 + mtl][nt2][rg]);
                            // permuted C-row: key = ks*32 + quad*8 + mtl*4 + rg
                            if (diag && (ks * 32 + quad * 8 + mtl * 4 + rg >
                                         nt2 * 16 + cl + qhalf * 32))
                                e = 0.0f;
                            pv[rg] = e;
                        }
                        dw[mtl * 2 + 0] = pk_bf16(pv[1], pv[0]);  // keys +0,+1
                        dw[mtl * 2 + 1] = pk_bf16(pv[3], pv[2]);  // keys +2,+3
                    }
                    union { uint4 u; bf16x8 v; } cv;
                    cv.u = make_uint4(dw[0], dw[1], dw[2], dw[3]);
                    pf[nt2] = cv.v;
                }
                // PV: O += P V ; l += P.1   (k = 32 keys of this pass)
                __builtin_amdgcn_s_setprio(1);
#pragma unroll
                for (int mt2 = 0; mt2 < 2; mt2++)
                    lacc[mt2] = __builtin_amdgcn_mfma_f32_16x16x32_bf16(
                        pf[mt2], ones, lacc[mt2], 0, 0, 0);
#pragma unroll
                for (int nt = 0; nt < 4; nt++) {
                    int r = nt * 16 + cl, cc = ks * 4 + quad;
                    bf16x8 vf = *(const bf16x8*)&Vl[(r * 8 + (cc ^ (r & 7))) * 8];
#pragma unroll
                    for (int mt2 = 0; mt2 < 2; mt2++)
                        oacc[mt2][nt] = __builtin_amdgcn_mfma_f32_16x16x32_bf16(
                            pf[mt2], vf, oacc[mt2][nt], 0, 0, 0);
                }
                __builtin_amdgcn_s_setprio(0);
            }
        }
        __syncthreads();  // drains this iteration's prefetch; syncs buffers
    }

    // ---- pair combine per group: p=1 writes partials, p=0 adds + stores ----
    if (p == 1) {
#pragma unroll
        for (int mt2 = 0; mt2 < 2; mt2++)
#pragma unroll
            for (int rg = 0; rg < 4; rg++) {
                int row = qhalf * 32 + mt2 * 16 + quad * 4 + rg;
                if (cl == 0) Ll[row] = lacc[mt2][rg];
#pragma unroll
                for (int nt = 0; nt < 4; nt++)
                    Cmb[row * 68 + nt * 16 + cl] = oacc[mt2][nt][rg];
            }
    }
    __syncthreads();
    if (p == 0) {
        const int b = bh >> 4, h = bh & 15;
#pragma unroll
        for (int mt2 = 0; mt2 < 2; mt2++)
#pragma unroll
            for (int rg = 0; rg < 4; rg++) {
                int row = qhalf * 32 + mt2 * 16 + quad * 4 + rg;
                float inv = 1.0f / (lacc[mt2][rg] + Ll[row]);
                int t = qbase + row;
#pragma unroll
                for (int nt = 0; nt < 4; nt++) {
                    int hs = nt * 16 + cl;
                    float val = oacc[mt2][nt][rg] + Cmb[row * 68 + nt * 16 + cl];
                    og[((size_t)(b * 2048 + t)) * 1024 + h * 64 + hs] = f2bf(val * inv);
                }
            }
    }
}

// ---------------------------------------------------------------------------
extern "C" void kernel_launch(void* const* d_in, const int* in_sizes, int n_in,
                              void* d_out, int out_size, void* d_ws, size_t ws_size,
                              hipStream_t stream) {
    const float* x = (const float*)d_in[0];
    const float* Wq = (const float*)d_in[1];
    const float* Wk = (const float*)d_in[2];
    const float* Wv = (const float*)d_in[3];
    const float* Wp = (const float*)d_in[4];
    const float* bp = (const float*)d_in[5];
    float* out = (float*)d_out;

    unsigned short* xb = (unsigned short*)d_ws;      // 8 MB
    unsigned short* wt3 = xb + (size_t)Mm * Ee;      // 6 MB (Q,K,V transposed)
    unsigned short* wpt = wt3 + (size_t)3 * Ee * Ee; // 2 MB
    unsigned short* qb = wpt + (size_t)Ee * Ee;      // 8 MB each
    unsigned short* kb = qb + (size_t)Mm * Ee;
    unsigned short* vtb = kb + (size_t)Mm * Ee;
    unsigned short* ab = vtb + (size_t)Mm * Ee;

    prep<<<dim3(16, 16, 5), dim3(256), 0, stream>>>(x, Wq, Wk, Wv, Wp, xb, wt3, wpt);
    gemm_qkv<<<dim3(768), dim3(256), 0, stream>>>(xb, wt3, qb, kb, vtb);
    attn_mfma<<<dim3(512), dim3(512), 0, stream>>>(qb, kb, vtb, ab);
    gemm_out<<<dim3(512), dim3(256), 0, stream>>>(ab, wpt, bp, out);
}